// Round 1
// 138.407 us; speedup vs baseline: 1.0005x; 1.0005x over previous
//
#include <hip/hip_runtime.h>
#include <hip/hip_bf16.h>
#include <math.h>

#define NQ 196
#define BATCH 4
#define HD 512            // H * D_K == D_MODEL
#define NH 8
#define DK 64
#define MROWS 784         // BATCH*NQ
#define MPAD 832          // 13*64: GEMM M-tile overhang rows (garbage, masked)

typedef __attribute__((ext_vector_type(8))) short short8;
typedef __attribute__((ext_vector_type(4))) short short4v;
typedef __attribute__((ext_vector_type(4))) float float4v;

__device__ __forceinline__ float b2f(short s) {
  return __uint_as_float(((unsigned)(unsigned short)s) << 16);
}
__device__ __forceinline__ short f2b(float x) {
  return __builtin_bit_cast(short, __float2bfloat16(x));
}
__device__ __forceinline__ float fexp2(float x) {
  float r; asm("v_exp_f32 %0, %1" : "=v"(r) : "v"(x)); return r;
}
__device__ __forceinline__ float frcp(float x) {
  float r; asm("v_rcp_f32 %0, %1" : "=v"(r) : "v"(x)); return r;
}
__device__ __forceinline__ void cvt4(float4 v, short4v& hi, short4v& lo) {
  float x[4] = {v.x, v.y, v.z, v.w};
  #pragma unroll
  for (int i = 0; i < 4; ++i) {
    hi[i] = f2b(x[i]);
    lo[i] = f2b(x[i] - b2f(hi[i]));
  }
}
__device__ __forceinline__ void gload_lds16(const void* g, void* l) {
  __builtin_amdgcn_global_load_lds(
      (const __attribute__((address_space(1))) unsigned int*)g,
      (__attribute__((address_space(3))) unsigned int*)l, 16, 0, 0);
}

// ---------------- split fp32 -> bf16 hi/lo (weights + X inputs) ----------------
struct WSplitArgs { const float* src[7]; short* hi[7]; short* lo[7]; int nblk[7]; };

__global__ __launch_bounds__(256)
void wsplit_kernel(WSplitArgs a) {
  int b = blockIdx.x, seg = 0;
  while (seg < 6 && b >= a.nblk[seg]) { b -= a.nblk[seg]; ++seg; }
  const size_t off = (size_t)b * 2048 + (size_t)threadIdx.x * 8;
  const float* src = a.src[seg] + off;
  float4 v0 = *(const float4*)(src);
  float4 v1 = *(const float4*)(src + 4);
  short4v h0, l0, h1, l1;
  cvt4(v0, h0, l0); cvt4(v1, h1, l1);
  short8 vh = {h0[0],h0[1],h0[2],h0[3],h1[0],h1[1],h1[2],h1[3]};
  short8 vl = {l0[0],l0[1],l0[2],l0[3],l1[0],l1[1],l1[2],l1[3]};
  *(short8*)(a.hi[seg] + off) = vh;
  *(short8*)(a.lo[seg] + off) = vl;
}

// ======== bf16x3 MFMA GEMM, 64x64 tile, BK=64, double-buffered DMA ==========
// 512 thr = 8 waves (4m x 2n); wave out = 16x32 (2 acc frags).
// All operands pre-split bf16; staging is pure global_load_lds (linear dest,
// inverse-XOR-swizzled source; frag reads apply byte ^= (row&7)<<4).
struct GemmArgs {
  const short* Ah[3]; const short* Al[3];
  const short* Bh[3]; const short* Bl[3];
  const float* bias[3];
  float* Cf[3]; short* Ch[3]; short* Cl[3]; const float* gate[3];
};

__global__ __launch_bounds__(512)
void mgemm(GemmArgs p, int M, int N, int K) {
  const int z = blockIdx.z;
  const short* __restrict__ Ah = p.Ah[z];
  const short* __restrict__ Al = p.Al[z];
  const short* __restrict__ Bh = p.Bh[z];
  const short* __restrict__ Bl = p.Bl[z];

  __shared__ short smem[32768];      // 64 KB: [buf][arr 0..3][64*64]
  const int t = threadIdx.x;
  const int ln = t & 63, lm = ln & 15, quad = ln >> 4;
  const int w = t >> 6;
  const int wm = w >> 1, wn = w & 1;
  const int m0 = blockIdx.x << 6, n0 = blockIdx.y << 6;

  // DMA staging: thread t -> tile row sr = t>>3, source col pre-swizzled so
  // linear LDS write (t*16 B) lands at swizzled position.
  const int sr = t >> 3;
  const int sc = ((t & 7) ^ (sr & 7)) << 3;          // shorts
  const short* gA_h = Ah + (size_t)(m0 + sr) * K + sc;
  const short* gA_l = Al + (size_t)(m0 + sr) * K + sc;
  const short* gB_h = Bh + (size_t)(n0 + sr) * K + sc;
  const short* gB_l = Bl + (size_t)(n0 + sr) * K + sc;
  const int ldst = t * 8;                            // shorts (t*16 bytes)

  float4v acc0 = {0.f,0.f,0.f,0.f}, acc1 = {0.f,0.f,0.f,0.f};

  gload_lds16(gA_h, &smem[0     + ldst]);
  gload_lds16(gA_l, &smem[4096  + ldst]);
  gload_lds16(gB_h, &smem[8192  + ldst]);
  gload_lds16(gB_l, &smem[12288 + ldst]);

  const int NT = K >> 6;                             // 8
  const int ar = (wm << 4) + lm;                     // A tile row
  const int br0 = (wn << 5) + lm, br1 = br0 + 16;    // B tile rows
  const int swz = (lm & 7) << 3;                     // same for ar/br0/br1

  for (int kt = 0; kt < NT; ++kt) {
    const int buf = kt & 1;
    __syncthreads();                                 // buf ready (DMA drained)
    if (kt + 1 < NT) {
      const int kb = (kt + 1) << 6;
      short* nb = &smem[(buf ^ 1) << 14];
      gload_lds16(gA_h + kb, nb + 0     + ldst);
      gload_lds16(gA_l + kb, nb + 4096  + ldst);
      gload_lds16(gB_h + kb, nb + 8192  + ldst);
      gload_lds16(gB_l + kb, nb + 12288 + ldst);
    }
    const short* Sb = &smem[buf << 14];
    #pragma unroll
    for (int h = 0; h < 2; ++h) {
      const int c = (h << 5) + (quad << 3);
      const int cs = c ^ swz;
      short8 a_h = *(const short8*)&Sb[         ar  * 64 + cs];
      short8 a_l = *(const short8*)&Sb[4096  +  ar  * 64 + cs];
      short8 b0h = *(const short8*)&Sb[8192  +  br0 * 64 + cs];
      short8 b0l = *(const short8*)&Sb[12288 +  br0 * 64 + cs];
      short8 b1h = *(const short8*)&Sb[8192  +  br1 * 64 + cs];
      short8 b1l = *(const short8*)&Sb[12288 +  br1 * 64 + cs];
      acc0 = __builtin_amdgcn_mfma_f32_16x16x32_bf16(a_h, b0h, acc0, 0,0,0);
      acc0 = __builtin_amdgcn_mfma_f32_16x16x32_bf16(a_h, b0l, acc0, 0,0,0);
      acc0 = __builtin_amdgcn_mfma_f32_16x16x32_bf16(a_l, b0h, acc0, 0,0,0);
      acc1 = __builtin_amdgcn_mfma_f32_16x16x32_bf16(a_h, b1h, acc1, 0,0,0);
      acc1 = __builtin_amdgcn_mfma_f32_16x16x32_bf16(a_h, b1l, acc1, 0,0,0);
      acc1 = __builtin_amdgcn_mfma_f32_16x16x32_bf16(a_l, b1h, acc1, 0,0,0);
    }
  }

  const float* bias = p.bias[z];
  const float* gate = p.gate[z];
  float* Cf = p.Cf[z]; short* Ch = p.Ch[z]; short* Cl = p.Cl[z];
  #pragma unroll
  for (int nf = 0; nf < 2; ++nf) {
    const float4v a = nf ? acc1 : acc0;
    const int n = n0 + (wn << 5) + (nf << 4) + lm;
    const float bv = bias[n];
    #pragma unroll
    for (int r = 0; r < 4; ++r) {
      const int m = m0 + (wm << 4) + (quad << 2) + r;
      if (m < M) {
        float c = a[r] + bv;
        if (gate) {
          const float qg = gate[(size_t)m * N + n];
          c = __fdividef(c, 1.f + __expf(-qg * c));  // sigmoid(qg*c)*c
        }
        if (Cf) Cf[(size_t)m * N + n] = c;
        if (Ch) {
          const short hi = f2b(c);
          Ch[(size_t)m * N + n] = hi;
          Cl[(size_t)m * N + n] = f2b(c - b2f(hi));
        }
      }
    }
  }
}

// ======== fused attention: scores (MFMA) + softmax + gated PV, 512 thr ======
// One block per (q-tile 16, h, b); 8 waves. S and p never leave LDS.
// image is emitted directly as bf16 hi/lo for the final DMA GEMM.
__global__ __launch_bounds__(512)
void attn_fused(const short* __restrict__ qsh, const short* __restrict__ qsl,
                const short* __restrict__ ksh, const short* __restrict__ ksl,
                const float* __restrict__ qsg, const float* __restrict__ kpg,
                const float* __restrict__ vpg, const float* __restrict__ scg,
                short* __restrict__ imgh, short* __restrict__ imgl) {
  const int q0 = blockIdx.x * 16;
  const int h  = blockIdx.y;
  const int b  = blockIdx.z;
  const int t  = threadIdx.x;
  const int w = t >> 6, ln = t & 63;
  const int lm = ln & 15, quad = ln >> 4;
  const float L2E = 1.4426950408889634f;

  __shared__ __align__(16) float S[16][212];  // stride 848 B = 16B-aligned rows
  __shared__ float R[8][16][64];              // pv k-group partials (32 KB)

  // ---- phase 1: S = q_sig . k_p^T (bf16x3 MFMA), waves stride nt by 8 ----
  const size_t abase = ((size_t)(b * NQ) + q0 + lm) * HD + h * DK + (quad << 3);
  short8 ah0 = *(const short8*)(qsh + abase);
  short8 ah1 = *(const short8*)(qsh + abase + 32);
  short8 al0 = *(const short8*)(qsl + abase);
  short8 al1 = *(const short8*)(qsl + abase + 32);

  for (int nt = w; nt < 13; nt += 8) {
    const size_t bbase = ((size_t)(b * NQ) + nt * 16 + lm) * HD + h * DK + (quad << 3);
    short8 bh0 = *(const short8*)(ksh + bbase);
    short8 bh1 = *(const short8*)(ksh + bbase + 32);
    short8 bl0 = *(const short8*)(ksl + bbase);
    short8 bl1 = *(const short8*)(ksl + bbase + 32);
    float4v acc = {0.f, 0.f, 0.f, 0.f};
    acc = __builtin_amdgcn_mfma_f32_16x16x32_bf16(ah0, bh0, acc, 0,0,0);
    acc = __builtin_amdgcn_mfma_f32_16x16x32_bf16(ah1, bh1, acc, 0,0,0);
    acc = __builtin_amdgcn_mfma_f32_16x16x32_bf16(ah0, bl0, acc, 0,0,0);
    acc = __builtin_amdgcn_mfma_f32_16x16x32_bf16(ah1, bl1, acc, 0,0,0);
    acc = __builtin_amdgcn_mfma_f32_16x16x32_bf16(al0, bh0, acc, 0,0,0);
    acc = __builtin_amdgcn_mfma_f32_16x16x32_bf16(al1, bh1, acc, 0,0,0);
    #pragma unroll
    for (int r = 0; r < 4; ++r)
      S[(quad << 2) + r][nt * 16 + lm] = acc[r];
  }
  __syncthreads();

  // ---- phase 2: softmax in place (wave w: rows 2w, 2w+1) ----
  for (int i = 0; i < 2; ++i) {
    const int rr = (w << 1) + i;
    const int q = q0 + rr;
    const bool qok = q < NQ;
    const float* srow = scg + ((size_t)h * NQ + (qok ? q : 0)) * NQ;
    float att[4];
    #pragma unroll
    for (int j = 0; j < 4; ++j) {
      const int c = ln + (j << 6);
      att[j] = -1e30f;
      if (c < NQ) att[j] = S[rr][c] * srow[c] * L2E;
    }
    float m = fmaxf(fmaxf(att[0], att[1]), fmaxf(att[2], att[3]));
    #pragma unroll
    for (int off = 32; off; off >>= 1) m = fmaxf(m, __shfl_xor(m, off, 64));
    float e[4], s = 0.f;
    #pragma unroll
    for (int j = 0; j < 4; ++j) { e[j] = fexp2(att[j] - m); s += e[j]; }
    #pragma unroll
    for (int off = 32; off; off >>= 1) s += __shfl_xor(s, off, 64);
    const float rinv = __fdividef(1.f, s);
    #pragma unroll
    for (int j = 0; j < 4; ++j) {
      const int c = ln + (j << 6);
      if (c < NQ) S[rr][c] = e[j] * rinv;
    }
  }
  __syncthreads();

  // ---- phase 3: gated PV. thread = (d = ln, kgroup = w of 8). ----
  // k-ranges 4-aligned (7x24 + 28) so S is read via ds_read_b128 (4 k / read).
  const int d = ln;
  const int kg = w;
  const int kbeg = kg * 24;
  const int kend = (kg == 7) ? 196 : kbeg + 24;
  const float LOG2E = 1.4426950408889634f;

  float nqs[16];
  #pragma unroll
  for (int qi = 0; qi < 16; ++qi) {
    const int row = min(b * NQ + q0 + qi, MROWS - 1);   // clamp tile overhang
    nqs[qi] = -qsg[(size_t)row * HD + h * DK + d] * LOG2E;
  }
  const float* kp = kpg + ((size_t)(b * NQ)) * HD + h * DK + d;
  const float* vp = vpg + ((size_t)(b * NQ)) * HD + h * DK + d;

  float acc[16];
  #pragma unroll
  for (int qi = 0; qi < 16; ++qi) acc[qi] = 0.f;

  for (int k = kbeg; k < kend; k += 4) {
    const float kv0 = kp[(size_t)(k + 0) * HD];
    const float kv1 = kp[(size_t)(k + 1) * HD];
    const float kv2 = kp[(size_t)(k + 2) * HD];
    const float kv3 = kp[(size_t)(k + 3) * HD];
    const float vv0 = vp[(size_t)(k + 0) * HD];
    const float vv1 = vp[(size_t)(k + 1) * HD];
    const float vv2 = vp[(size_t)(k + 2) * HD];
    const float vv3 = vp[(size_t)(k + 3) * HD];
    #pragma unroll
    for (int qi = 0; qi < 16; ++qi) {
      const float4 s4 = *(const float4*)&S[qi][k];
      acc[qi] += s4.x * (vv0 * frcp(1.f + fexp2(nqs[qi] * kv0)));
      acc[qi] += s4.y * (vv1 * frcp(1.f + fexp2(nqs[qi] * kv1)));
      acc[qi] += s4.z * (vv2 * frcp(1.f + fexp2(nqs[qi] * kv2)));
      acc[qi] += s4.w * (vv3 * frcp(1.f + fexp2(nqs[qi] * kv3)));
    }
  }
  #pragma unroll
  for (int qi = 0; qi < 16; ++qi) R[kg][qi][d] = acc[qi];
  __syncthreads();

  #pragma unroll
  for (int j = 0; j < 2; ++j) {
    const int idx = t + (j << 9);
    const int qi = idx >> 6, dd = idx & 63;
    const int q = q0 + qi;
    if (q < NQ) {
      float s = 0.f;
      #pragma unroll
      for (int kk = 0; kk < 8; ++kk) s += R[kk][qi][dd];
      const size_t o = ((size_t)(b * NQ) + q) * HD + h * DK + dd;
      const short hi = f2b(s);
      imgh[o] = hi;
      imgl[o] = f2b(s - b2f(hi));
    }
  }
}

extern "C" void kernel_launch(void* const* d_in, const int* in_sizes, int n_in,
                              void* d_out, int out_size, void* d_ws, size_t ws_size,
                              hipStream_t stream) {
  const float* queries = (const float*)d_in[0];
  const float* keys    = (const float*)d_in[1];
  const float* values  = (const float*)d_in[2];
  const float* Wq = (const float*)d_in[3];
  const float* bq = (const float*)d_in[4];
  const float* Wk = (const float*)d_in[5];
  const float* bk = (const float*)d_in[6];
  const float* Wv = (const float*)d_in[7];
  const float* bv = (const float*)d_in[8];
  const float* Wo = (const float*)d_in[9];
  const float* bo = (const float*)d_in[10];
  const float* scale = (const float*)d_in[11];

  char* base = (char*)d_ws;
  const size_t FB = sizeof(float);
  const size_t NELF  = (size_t)MROWS * HD;   // 401408
  const size_t NELPS = (size_t)MPAD * HD;    // 425984
  const size_t WEL   = (size_t)HD * HD;      // 262144

  size_t o = 0;
  float* q_sig = (float*)(base + o); o += NELF * FB;
  float* k_p   = (float*)(base + o); o += NELF * FB;
  float* v_p   = (float*)(base + o); o += NELF * FB;
  short* qsh = (short*)(base + o); o += NELPS * 2;
  short* qsl = (short*)(base + o); o += NELPS * 2;
  short* ksh = (short*)(base + o); o += NELPS * 2;
  short* ksl = (short*)(base + o); o += NELPS * 2;
  short* imgh = (short*)(base + o); o += NELPS * 2;
  short* imgl = (short*)(base + o); o += NELPS * 2;
  short* xqh = (short*)(base + o); o += NELPS * 2;
  short* xql = (short*)(base + o); o += NELPS * 2;
  short* xkh = (short*)(base + o); o += NELPS * 2;
  short* xkl = (short*)(base + o); o += NELPS * 2;
  short* xvh = (short*)(base + o); o += NELPS * 2;
  short* xvl = (short*)(base + o); o += NELPS * 2;
  short* Wqh = (short*)(base + o); o += WEL * 2;
  short* Wql = (short*)(base + o); o += WEL * 2;
  short* Wkh = (short*)(base + o); o += WEL * 2;
  short* Wkl = (short*)(base + o); o += WEL * 2;
  short* Wvh = (short*)(base + o); o += WEL * 2;
  short* Wvl = (short*)(base + o); o += WEL * 2;
  short* Woh = (short*)(base + o); o += WEL * 2;
  short* Wol = (short*)(base + o); o += WEL * 2;

  // 0) split weights + X inputs once (weights: 128 blocks ea, X: 196 blocks ea)
  WSplitArgs wa;
  wa.src[0] = Wq;      wa.hi[0] = Wqh; wa.lo[0] = Wql; wa.nblk[0] = 128;
  wa.src[1] = Wk;      wa.hi[1] = Wkh; wa.lo[1] = Wkl; wa.nblk[1] = 128;
  wa.src[2] = Wv;      wa.hi[2] = Wvh; wa.lo[2] = Wvl; wa.nblk[2] = 128;
  wa.src[3] = Wo;      wa.hi[3] = Woh; wa.lo[3] = Wol; wa.nblk[3] = 128;
  wa.src[4] = queries; wa.hi[4] = xqh; wa.lo[4] = xql; wa.nblk[4] = 196;
  wa.src[5] = keys;    wa.hi[5] = xkh; wa.lo[5] = xkl; wa.nblk[5] = 196;
  wa.src[6] = values;  wa.hi[6] = xvh; wa.lo[6] = xvl; wa.nblk[6] = 196;
  wsplit_kernel<<<1100, 256, 0, stream>>>(wa);

  // 1) projections: z0 q_sig (fp32 + split), z1 k_p (fp32 + split), z2 v_p (fp32)
  GemmArgs gp;
  gp.Ah[0] = xqh; gp.Al[0] = xql; gp.Bh[0] = Wqh; gp.Bl[0] = Wql; gp.bias[0] = bq;
  gp.Cf[0] = q_sig; gp.Ch[0] = qsh; gp.Cl[0] = qsl; gp.gate[0] = nullptr;
  gp.Ah[1] = xkh; gp.Al[1] = xkl; gp.Bh[1] = Wkh; gp.Bl[1] = Wkl; gp.bias[1] = bk;
  gp.Cf[1] = k_p; gp.Ch[1] = ksh; gp.Cl[1] = ksl; gp.gate[1] = nullptr;
  gp.Ah[2] = xvh; gp.Al[2] = xvl; gp.Bh[2] = Wvh; gp.Bl[2] = Wvl; gp.bias[2] = bv;
  gp.Cf[2] = v_p; gp.Ch[2] = nullptr; gp.Cl[2] = nullptr; gp.gate[2] = nullptr;
  mgemm<<<dim3(MPAD/64, HD/64, 3), 512, 0, stream>>>(gp, MROWS, HD, HD);

  // 2) fused scores + softmax + gated PV -> image (bf16 hi/lo)
  attn_fused<<<dim3(13, NH, BATCH), 512, 0, stream>>>(
      qsh, qsl, ksh, ksl, q_sig, k_p, v_p, scale, imgh, imgl);

  // 3) out = image @ Wo^T + bo, gated by q_sig
  GemmArgs go;
  go.Ah[0] = imgh; go.Al[0] = imgl; go.Bh[0] = Woh; go.Bl[0] = Wol; go.bias[0] = bo;
  go.Cf[0] = (float*)d_out; go.Ch[0] = nullptr; go.Cl[0] = nullptr; go.gate[0] = q_sig;
  for (int i = 1; i < 3; ++i) {
    go.Ah[i] = nullptr; go.Al[i] = nullptr; go.Bh[i] = nullptr; go.Bl[i] = nullptr;
    go.bias[i] = nullptr; go.Cf[i] = nullptr; go.Ch[i] = nullptr; go.Cl[i] = nullptr;
    go.gate[i] = nullptr;
  }
  mgemm<<<dim3(MPAD/64, HD/64, 1), 512, 0, stream>>>(go, MROWS, HD, HD);
}